// Round 4
// baseline (295.038 us; speedup 1.0000x reference)
//
#include <hip/hip_runtime.h>
#include <math.h>

#define BB 1024   // batch
#define VV 256    // variables
#define KK 64     // categories
#define N0 8192   // input nodes
#define CC 32     // sum-node children
#define W  128    // batch chunk = B/8; one chunk pinned per XCD via blockIdx&7

#define LOG2E 1.4426950408889634f
#define LN2   0.6931471805599453f

static __device__ __forceinline__ float fexp2(float x) {
#if __has_builtin(__builtin_amdgcn_exp2f)
    return __builtin_amdgcn_exp2f(x);       // v_exp_f32, 1 inst
#else
    return __expf(x * LN2);
#endif
}
static __device__ __forceinline__ float flog2(float x) {
#if __has_builtin(__builtin_amdgcn_logf)
    return __builtin_amdgcn_logf(x);        // v_log_f32, 1 inst
#else
    return __logf(x) * LOG2E;
#endif
}

// ---------------------------------------------------------------------------
// transpose x [B,V] -> xt [V,B]
// ---------------------------------------------------------------------------
__global__ void k_transpose_x(const int* __restrict__ x, int* __restrict__ xt) {
    int idx = blockIdx.x * blockDim.x + threadIdx.x;
    int v = idx >> 10;
    int b = idx & (BB - 1);
    xt[idx] = x[b * VV + v];
}

// ---------------------------------------------------------------------------
// log2-softmax rows of in_logits -> lp [N0][K]. One wave per row (K=64).
// ---------------------------------------------------------------------------
__global__ void __launch_bounds__(256) k_logsoftmax(const float* __restrict__ logits,
                                                    float* __restrict__ lp) {
    int row = blockIdx.x * 4 + (threadIdx.x >> 6);
    int k = threadIdx.x & 63;
    float l = logits[(size_t)row * KK + k];
    float m = l;
    #pragma unroll
    for (int d = 32; d; d >>= 1) m = fmaxf(m, __shfl_xor(m, d));
    float s = __expf(l - m);
    #pragma unroll
    for (int d = 32; d; d >>= 1) s += __shfl_xor(s, d);
    lp[(size_t)row * KK + k] = (l - m) * LOG2E - flog2(s);  // log2 domain
}

// ---------------------------------------------------------------------------
// input gather: block g -> chunk (g&7); 8 input nodes per block, 1 col/thread.
// nm[(1+i)*B + b] = lp[i][ xt[var(i)*B + b] ]   (log2 domain)
// ---------------------------------------------------------------------------
__global__ void __launch_bounds__(W) k_input_gather(const float* __restrict__ lp,
                                                    const int* __restrict__ xt,
                                                    float* __restrict__ nm) {
    int g = blockIdx.x;
    int chunk = g & 7;
    int i0 = (g >> 3) * 8;
    int b = chunk * W + threadIdx.x;
    int v = i0 >> 5;
    int xv = xt[v * BB + b];
    #pragma unroll
    for (int j = 0; j < 8; ++j) {
        int i = i0 + j;
        nm[(size_t)(1 + i) * BB + b] = lp[(size_t)i * KK + xv];
    }
}

// ---------------------------------------------------------------------------
// fused prod+sum layer (log2 domain).
// Block = 256 threads = 8 sum nodes x 32 lanes; lane covers 4 batch cols
// (float4). chunk = blockIdx&7 pins batch cols [chunk*128, +128) to one XCD.
// Per child c: element e = cids[s][c]-1, computed on the fly as
//   nm[pids[e][0]] + nm[pids[e][1]]  (no em materialization).
// logsumexp in 2 groups of 16 children (v[16] float4 = 64 VGPR) + combine.
// ---------------------------------------------------------------------------
__global__ void k_fused_sum(const float* __restrict__ nm,
                            const int* __restrict__ pids,
                            const int* __restrict__ cids,
                            const float* __restrict__ w,
                            float* __restrict__ out,
                            int S, float out_scale) {
    int g = blockIdx.x;
    int chunk = g & 7;
    int sub = threadIdx.x >> 5;
    int lane = threadIdx.x & 31;
    int s = (g >> 3) * 8 + sub;
    __shared__ float slw[8][CC];
    __shared__ int sp0[8][CC];
    __shared__ int sp1[8][CC];
    bool valid = s < S;
    if (valid) {
        float lw = w[s * CC + lane];
        float m = lw;
        #pragma unroll
        for (int d = 16; d; d >>= 1) m = fmaxf(m, __shfl_xor(m, d, 32));
        float su = __expf(lw - m);
        #pragma unroll
        for (int d = 16; d; d >>= 1) su += __shfl_xor(su, d, 32);
        slw[sub][lane] = (lw - m) * LOG2E - flog2(su);   // log2 weights
        int e = cids[s * CC + lane] - 1;                 // element id -> pids row
        sp0[sub][lane] = pids[e * 2 + 0];
        sp1[sub][lane] = pids[e * 2 + 1];
    }
    __syncthreads();
    if (!valid) return;
    int b = chunk * W + lane * 4;

    float4 mx = {-INFINITY, -INFINITY, -INFINITY, -INFINITY};
    float4 su = {0.f, 0.f, 0.f, 0.f};
    #pragma unroll
    for (int grp = 0; grp < 2; ++grp) {
        float4 v[16];
        float4 gmx = {-INFINITY, -INFINITY, -INFINITY, -INFINITY};
        #pragma unroll
        for (int c = 0; c < 16; ++c) {
            int cc = grp * 16 + c;
            const float4 a = *(const float4*)(nm + (size_t)sp0[sub][cc] * BB + b);
            const float4 bb = *(const float4*)(nm + (size_t)sp1[sub][cc] * BB + b);
            float lw = slw[sub][cc];
            float4 t;
            t.x = a.x + bb.x + lw; t.y = a.y + bb.y + lw;
            t.z = a.z + bb.z + lw; t.w = a.w + bb.w + lw;
            v[c] = t;
            gmx.x = fmaxf(gmx.x, t.x); gmx.y = fmaxf(gmx.y, t.y);
            gmx.z = fmaxf(gmx.z, t.z); gmx.w = fmaxf(gmx.w, t.w);
        }
        float4 gsu = {0.f, 0.f, 0.f, 0.f};
        #pragma unroll
        for (int c = 0; c < 16; ++c) {
            gsu.x += fexp2(v[c].x - gmx.x);
            gsu.y += fexp2(v[c].y - gmx.y);
            gsu.z += fexp2(v[c].z - gmx.z);
            gsu.w += fexp2(v[c].w - gmx.w);
        }
        if (grp == 0) {
            mx = gmx; su = gsu;
        } else {
            float4 nmx;
            nmx.x = fmaxf(mx.x, gmx.x); nmx.y = fmaxf(mx.y, gmx.y);
            nmx.z = fmaxf(mx.z, gmx.z); nmx.w = fmaxf(mx.w, gmx.w);
            su.x = su.x * fexp2(mx.x - nmx.x) + gsu.x * fexp2(gmx.x - nmx.x);
            su.y = su.y * fexp2(mx.y - nmx.y) + gsu.y * fexp2(gmx.y - nmx.y);
            su.z = su.z * fexp2(mx.z - nmx.z) + gsu.z * fexp2(gmx.z - nmx.z);
            su.w = su.w * fexp2(mx.w - nmx.w) + gsu.w * fexp2(gmx.w - nmx.w);
            mx = nmx;
        }
    }
    float4 o;
    o.x = (mx.x + flog2(su.x)) * out_scale;
    o.y = (mx.y + flog2(su.y)) * out_scale;
    o.z = (mx.z + flog2(su.z)) * out_scale;
    o.w = (mx.w + flog2(su.w)) * out_scale;
    *(float4*)(out + (size_t)s * BB + b) = o;
}

// ---------------------------------------------------------------------------
// Launch. nm rows = global node ids 0..15360 (row 0 never referenced).
// Intermediate nm is in log2 domain; root output scaled back by ln2.
// ---------------------------------------------------------------------------
extern "C" void kernel_launch(void* const* d_in, const int* in_sizes, int n_in,
                              void* d_out, int out_size, void* d_ws, size_t ws_size,
                              hipStream_t stream) {
    const int*   x         = (const int*)  d_in[0];
    const float* in_logits = (const float*)d_in[1];
    const float* w1        = (const float*)d_in[2];
    const float* w2        = (const float*)d_in[3];
    const float* w3        = (const float*)d_in[4];
    const float* w4        = (const float*)d_in[5];
    const int*   pids1     = (const int*)  d_in[6];
    const int*   pids2     = (const int*)  d_in[7];
    const int*   pids3     = (const int*)  d_in[8];
    const int*   pids4     = (const int*)  d_in[9];
    const int*   cids1     = (const int*)  d_in[10];
    const int*   cids2     = (const int*)  d_in[11];
    const int*   cids3     = (const int*)  d_in[12];
    const int*   cids4     = (const int*)  d_in[13];
    float* out = (float*)d_out;

    float* nm = (float*)d_ws;                       // 15361 * 1024 floats
    float* lp = nm + (size_t)15361 * BB;            //  8192 * 64 floats
    int*   xt = (int*)(lp + (size_t)N0 * KK);       //   256 * 1024 ints

    k_transpose_x <<<(VV * BB) / 256, 256, 0, stream>>>(x, xt);
    k_logsoftmax  <<<N0 / 4, 256, 0, stream>>>(in_logits, lp);
    k_input_gather<<<(N0 / 8) * 8, W, 0, stream>>>(lp, xt, nm);

    // fused prod+sum layers; outputs at global-id row starts 8193/12289/14337
    k_fused_sum<<<(4096 / 8) * 8, 256, 0, stream>>>(nm, pids1, cids1, w1,
                                                    nm + (size_t)8193 * BB, 4096, 1.0f);
    k_fused_sum<<<(2048 / 8) * 8, 256, 0, stream>>>(nm, pids2, cids2, w2,
                                                    nm + (size_t)12289 * BB, 2048, 1.0f);
    k_fused_sum<<<(1024 / 8) * 8, 256, 0, stream>>>(nm, pids3, cids3, w3,
                                                    nm + (size_t)14337 * BB, 1024, 1.0f);
    k_fused_sum<<<1 * 8, 256, 0, stream>>>(nm, pids4, cids4, w4,
                                           out, 1, LN2);
}

// Round 5
// 190.723 us; speedup vs baseline: 1.5469x; 1.5469x over previous
//
#include <hip/hip_runtime.h>
#include <math.h>

#define BB 1024   // batch
#define VV 256    // variables
#define KK 64     // categories
#define N0 8192   // input nodes
#define CC 32     // sum-node children
#define W  128    // batch chunk = B/8; chunk (blockIdx&7) pinned per XCD

#define LOG2E 1.4426950408889634f
#define LN2   0.6931471805599453f

static __device__ __forceinline__ float fexp2(float x) {
    return __builtin_amdgcn_exp2f(x);       // v_exp_f32
}
static __device__ __forceinline__ float flog2(float x) {
    return __builtin_amdgcn_logf(x);        // v_log_f32
}

// ---------------------------------------------------------------------------
// transpose x [B,V] -> xt [V,B]
// ---------------------------------------------------------------------------
__global__ void k_transpose_x(const int* __restrict__ x, int* __restrict__ xt) {
    int idx = blockIdx.x * blockDim.x + threadIdx.x;
    int v = idx >> 10;
    int b = idx & (BB - 1);
    xt[idx] = x[b * VV + v];
}

// ---------------------------------------------------------------------------
// log2-softmax rows of in_logits -> lp [N0][K]. One wave per row (K=64).
// ---------------------------------------------------------------------------
__global__ void __launch_bounds__(256) k_logsoftmax(const float* __restrict__ logits,
                                                    float* __restrict__ lp) {
    int row = blockIdx.x * 4 + (threadIdx.x >> 6);
    int k = threadIdx.x & 63;
    float l = logits[(size_t)row * KK + k];
    float m = l;
    #pragma unroll
    for (int d = 32; d; d >>= 1) m = fmaxf(m, __shfl_xor(m, d));
    float s = __expf(l - m);
    #pragma unroll
    for (int d = 32; d; d >>= 1) s += __shfl_xor(s, d);
    lp[(size_t)row * KK + k] = (l - m) * LOG2E - flog2(s);  // log2 domain
}

// ---------------------------------------------------------------------------
// input gather: block g -> chunk (g&7); 8 input nodes per block, 1 col/thread.
// nm[(1+i)*B + b] = lp[i][ xt[var(i)*B + b] ]   (log2 domain)
// ---------------------------------------------------------------------------
__global__ void __launch_bounds__(W) k_input_gather(const float* __restrict__ lp,
                                                    const int* __restrict__ xt,
                                                    float* __restrict__ nm) {
    int g = blockIdx.x;
    int chunk = g & 7;
    int i0 = (g >> 3) * 8;
    int b = chunk * W + threadIdx.x;
    int v = i0 >> 5;                 // same variable for all 8 nodes
    int xv = xt[v * BB + b];
    #pragma unroll
    for (int j = 0; j < 8; ++j) {
        int i = i0 + j;
        nm[(size_t)(1 + i) * BB + b] = lp[(size_t)i * KK + xv];
    }
}

// ---------------------------------------------------------------------------
// product layer: block = 256 threads = 8 elements x 32 lanes, float4 cols.
// em[e*B + b..] = nm[p0*B + b..] + nm[p1*B + b..]   (log2 domain: add)
// ---------------------------------------------------------------------------
__global__ void __launch_bounds__(256) k_prod_layer(const float* __restrict__ nm,
                                                    const int* __restrict__ pids,
                                                    float* __restrict__ em) {
    int g = blockIdx.x;
    int chunk = g & 7;
    int sub = threadIdx.x >> 5;
    int lane = threadIdx.x & 31;
    int e = (g >> 3) * 8 + sub;
    int p0 = pids[e * 2 + 0];
    int p1 = pids[e * 2 + 1];
    int b = chunk * W + lane * 4;
    const float4 a = *(const float4*)(nm + (size_t)p0 * BB + b);
    const float4 c = *(const float4*)(nm + (size_t)p1 * BB + b);
    float4 o;
    o.x = a.x + c.x; o.y = a.y + c.y; o.z = a.z + c.z; o.w = a.w + c.w;
    *(float4*)(em + (size_t)e * BB + b) = o;
}

// ---------------------------------------------------------------------------
// sum layer (log2 domain): block = 256 threads = 8 sum nodes x 32 lanes,
// float4 cols. Children in 2 groups of 16 (v[16] = 64 VGPR) + online combine.
// out = (mx + log2(su)) * out_scale   (out_scale=1 inner, ln2 at root)
// ---------------------------------------------------------------------------
__global__ void __launch_bounds__(256) k_sum_layer(const float* __restrict__ em,
                                                   const int* __restrict__ cids,
                                                   const float* __restrict__ w,
                                                   float* __restrict__ out,
                                                   int S, float out_scale) {
    int g = blockIdx.x;
    int chunk = g & 7;
    int sub = threadIdx.x >> 5;
    int lane = threadIdx.x & 31;
    int s = (g >> 3) * 8 + sub;
    __shared__ float slw[8][CC];
    __shared__ int scid[8][CC];
    bool valid = s < S;
    if (valid) {
        float lw = w[s * CC + lane];
        float m = lw;
        #pragma unroll
        for (int d = 16; d; d >>= 1) m = fmaxf(m, __shfl_xor(m, d, 32));
        float su = __expf(lw - m);
        #pragma unroll
        for (int d = 16; d; d >>= 1) su += __shfl_xor(su, d, 32);
        slw[sub][lane] = (lw - m) * LOG2E - flog2(su);   // log2 weights
        scid[sub][lane] = cids[s * CC + lane] - 1;
    }
    __syncthreads();
    if (!valid) return;
    int b = chunk * W + lane * 4;

    float4 mx, su;
    #pragma unroll
    for (int grp = 0; grp < 2; ++grp) {
        float4 v[16];
        float4 gmx = {-INFINITY, -INFINITY, -INFINITY, -INFINITY};
        #pragma unroll
        for (int c = 0; c < 16; ++c) {
            int cc = grp * 16 + c;
            float4 t = *(const float4*)(em + (size_t)scid[sub][cc] * BB + b);
            float lw = slw[sub][cc];
            t.x += lw; t.y += lw; t.z += lw; t.w += lw;
            v[c] = t;
            gmx.x = fmaxf(gmx.x, t.x); gmx.y = fmaxf(gmx.y, t.y);
            gmx.z = fmaxf(gmx.z, t.z); gmx.w = fmaxf(gmx.w, t.w);
        }
        float4 gsu = {0.f, 0.f, 0.f, 0.f};
        #pragma unroll
        for (int c = 0; c < 16; ++c) {
            gsu.x += fexp2(v[c].x - gmx.x);
            gsu.y += fexp2(v[c].y - gmx.y);
            gsu.z += fexp2(v[c].z - gmx.z);
            gsu.w += fexp2(v[c].w - gmx.w);
        }
        if (grp == 0) {
            mx = gmx; su = gsu;
        } else {
            float4 nmx;
            nmx.x = fmaxf(mx.x, gmx.x); nmx.y = fmaxf(mx.y, gmx.y);
            nmx.z = fmaxf(mx.z, gmx.z); nmx.w = fmaxf(mx.w, gmx.w);
            su.x = su.x * fexp2(mx.x - nmx.x) + gsu.x * fexp2(gmx.x - nmx.x);
            su.y = su.y * fexp2(mx.y - nmx.y) + gsu.y * fexp2(gmx.y - nmx.y);
            su.z = su.z * fexp2(mx.z - nmx.z) + gsu.z * fexp2(gmx.z - nmx.z);
            su.w = su.w * fexp2(mx.w - nmx.w) + gsu.w * fexp2(gmx.w - nmx.w);
            mx = nmx;
        }
    }
    float4 o;
    o.x = (mx.x + flog2(su.x)) * out_scale;
    o.y = (mx.y + flog2(su.y)) * out_scale;
    o.z = (mx.z + flog2(su.z)) * out_scale;
    o.w = (mx.w + flog2(su.w)) * out_scale;
    *(float4*)(out + (size_t)s * BB + b) = o;
}

// ---------------------------------------------------------------------------
// Launch. nm rows = global node ids 0..15360 (row 0 never referenced).
// nm/em in log2 domain; root output scaled back by ln2.
// lp aliases em (lp consumed by input_gather before prod1 writes em).
// ---------------------------------------------------------------------------
extern "C" void kernel_launch(void* const* d_in, const int* in_sizes, int n_in,
                              void* d_out, int out_size, void* d_ws, size_t ws_size,
                              hipStream_t stream) {
    const int*   x         = (const int*)  d_in[0];
    const float* in_logits = (const float*)d_in[1];
    const float* w1        = (const float*)d_in[2];
    const float* w2        = (const float*)d_in[3];
    const float* w3        = (const float*)d_in[4];
    const float* w4        = (const float*)d_in[5];
    const int*   pids1     = (const int*)  d_in[6];
    const int*   pids2     = (const int*)  d_in[7];
    const int*   pids3     = (const int*)  d_in[8];
    const int*   pids4     = (const int*)  d_in[9];
    const int*   cids1     = (const int*)  d_in[10];
    const int*   cids2     = (const int*)  d_in[11];
    const int*   cids3     = (const int*)  d_in[12];
    const int*   cids4     = (const int*)  d_in[13];
    float* out = (float*)d_out;

    float* nm = (float*)d_ws;                       // 15361 * 1024 floats
    float* em = nm + (size_t)15361 * BB;            //  8192 * 1024 floats
    int*   xt = (int*)(em + (size_t)8192 * BB);     //   256 * 1024 ints
    float* lp = em;                                 //  8192 * 64 floats, aliased

    k_transpose_x <<<(VV * BB) / 256, 256, 0, stream>>>(x, xt);
    k_logsoftmax  <<<N0 / 4, 256, 0, stream>>>(in_logits, lp);
    k_input_gather<<<(N0 / 8) * 8, W, 0, stream>>>(lp, xt, nm);

    // layer pair 1: E=8192 -> S=4096 (global ids 8193..12288)
    k_prod_layer<<<(8192 / 8) * 8, 256, 0, stream>>>(nm, pids1, em);
    k_sum_layer <<<(4096 / 8) * 8, 256, 0, stream>>>(em, cids1, w1, nm + (size_t)8193 * BB, 4096, 1.0f);
    // layer pair 2: E=4096 -> S=2048 (ids 12289..14336)
    k_prod_layer<<<(4096 / 8) * 8, 256, 0, stream>>>(nm, pids2, em);
    k_sum_layer <<<(2048 / 8) * 8, 256, 0, stream>>>(em, cids2, w2, nm + (size_t)12289 * BB, 2048, 1.0f);
    // layer pair 3: E=2048 -> S=1024 (ids 14337..15360)
    k_prod_layer<<<(2048 / 8) * 8, 256, 0, stream>>>(nm, pids3, em);
    k_sum_layer <<<(1024 / 8) * 8, 256, 0, stream>>>(em, cids3, w3, nm + (size_t)14337 * BB, 1024, 1.0f);
    // layer pair 4: E=1024 -> root (direct to d_out, 1024 floats)
    k_prod_layer<<<(1024 / 8) * 8, 256, 0, stream>>>(nm, pids4, em);
    k_sum_layer <<<1 * 8, 256, 0, stream>>>(em, cids4, w4, out, 1, LN2);
}

// Round 6
// 174.318 us; speedup vs baseline: 1.6925x; 1.0941x over previous
//
#include <hip/hip_runtime.h>
#include <math.h>

#define BB 1024   // batch
#define VV 256    // variables
#define KK 64     // categories
#define N0 8192   // input nodes
#define CC 32     // sum-node children
#define W  128    // batch chunk = B/8; chunk (blockIdx&7) pinned per XCD

#define LOG2E 1.4426950408889634f
#define LN2   0.6931471805599453f

static __device__ __forceinline__ float fexp2(float x) {
    return __builtin_amdgcn_exp2f(x);
}
static __device__ __forceinline__ float flog2(float x) {
    return __builtin_amdgcn_logf(x);
}
static __device__ __forceinline__ float bf2f(unsigned short u) {
    unsigned int x = (unsigned int)u << 16;
    union { unsigned int i; float f; } c; c.i = x; return c.f;
}
static __device__ __forceinline__ unsigned short f2bf(float f) {
    union { float f; unsigned int i; } c; c.f = f;
    unsigned int r = c.i + 0x7FFFu + ((c.i >> 16) & 1u);  // RNE
    return (unsigned short)(r >> 16);
}

// ---------------------------------------------------------------------------
// transpose x [B,V] -> xt [V,B]
// ---------------------------------------------------------------------------
__global__ void k_transpose_x(const int* __restrict__ x, int* __restrict__ xt) {
    int idx = blockIdx.x * blockDim.x + threadIdx.x;
    int v = idx >> 10;
    int b = idx & (BB - 1);
    xt[idx] = x[b * VV + v];
}

// ---------------------------------------------------------------------------
// log2-softmax rows of in_logits -> lp [N0][K]. One wave per row (K=64).
// ---------------------------------------------------------------------------
__global__ void __launch_bounds__(256) k_logsoftmax(const float* __restrict__ logits,
                                                    float* __restrict__ lp) {
    int row = blockIdx.x * 4 + (threadIdx.x >> 6);
    int k = threadIdx.x & 63;
    float l = logits[(size_t)row * KK + k];
    float m = l;
    #pragma unroll
    for (int d = 32; d; d >>= 1) m = fmaxf(m, __shfl_xor(m, d));
    float s = __expf(l - m);
    #pragma unroll
    for (int d = 32; d; d >>= 1) s += __shfl_xor(s, d);
    lp[(size_t)row * KK + k] = (l - m) * LOG2E - flog2(s);  // log2 domain
}

// ---------------------------------------------------------------------------
// input gather: block g -> chunk (g&7); 8 input nodes per block, 1 col/thread.
// nm[(1+i)*B + b] = lp[i][ xt[var(i)*B + b] ]   (log2 domain, fp32)
// ---------------------------------------------------------------------------
__global__ void __launch_bounds__(W) k_input_gather(const float* __restrict__ lp,
                                                    const int* __restrict__ xt,
                                                    float* __restrict__ nm) {
    int g = blockIdx.x;
    int chunk = g & 7;
    int i0 = (g >> 3) * 8;
    int b = chunk * W + threadIdx.x;
    int v = i0 >> 5;
    int xv = xt[v * BB + b];
    #pragma unroll
    for (int j = 0; j < 8; ++j) {
        int i = i0 + j;
        nm[(size_t)(1 + i) * BB + b] = lp[(size_t)i * KK + xv];
    }
}

// ---------------------------------------------------------------------------
// product layer: block = 256 threads = 8 elements x 32 lanes, 4 cols/lane.
// reads nm fp32, writes em bf16 (RNE).  (log2 domain: product = add)
// ---------------------------------------------------------------------------
__global__ void __launch_bounds__(256) k_prod_layer(const float* __restrict__ nm,
                                                    const int* __restrict__ pids,
                                                    unsigned short* __restrict__ em) {
    int g = blockIdx.x;
    int chunk = g & 7;
    int sub = threadIdx.x >> 5;
    int lane = threadIdx.x & 31;
    int e = (g >> 3) * 8 + sub;
    int p0 = pids[e * 2 + 0];
    int p1 = pids[e * 2 + 1];
    int b = chunk * W + lane * 4;
    const float4 a = *(const float4*)(nm + (size_t)p0 * BB + b);
    const float4 c = *(const float4*)(nm + (size_t)p1 * BB + b);
    ushort4 o;
    o.x = f2bf(a.x + c.x); o.y = f2bf(a.y + c.y);
    o.z = f2bf(a.z + c.z); o.w = f2bf(a.w + c.w);
    *(ushort4*)(em + (size_t)e * BB + b) = o;
}

// ---------------------------------------------------------------------------
// sum layer (log2 domain): block = 256 threads = 8 sum nodes x 32 lanes,
// 4 cols/lane. em gathered as bf16x4 (8 B/child). Children in 2 groups of 16
// + online combine. Output nm fp32.
// ---------------------------------------------------------------------------
__global__ void __launch_bounds__(256) k_sum_layer(const unsigned short* __restrict__ em,
                                                   const int* __restrict__ cids,
                                                   const float* __restrict__ w,
                                                   float* __restrict__ out,
                                                   int S) {
    int g = blockIdx.x;
    int chunk = g & 7;
    int sub = threadIdx.x >> 5;
    int lane = threadIdx.x & 31;
    int s = (g >> 3) * 8 + sub;
    __shared__ float slw[8][CC];
    __shared__ int scid[8][CC];
    if (s < S) {
        float lw = w[s * CC + lane];
        float m = lw;
        #pragma unroll
        for (int d = 16; d; d >>= 1) m = fmaxf(m, __shfl_xor(m, d, 32));
        float su = __expf(lw - m);
        #pragma unroll
        for (int d = 16; d; d >>= 1) su += __shfl_xor(su, d, 32);
        slw[sub][lane] = (lw - m) * LOG2E - flog2(su);
        scid[sub][lane] = cids[s * CC + lane] - 1;
    }
    __syncthreads();
    if (s >= S) return;
    int b = chunk * W + lane * 4;

    float4 mx, su;
    #pragma unroll
    for (int grp = 0; grp < 2; ++grp) {
        float4 v[16];
        float4 gmx = {-INFINITY, -INFINITY, -INFINITY, -INFINITY};
        #pragma unroll
        for (int c = 0; c < 16; ++c) {
            int cc = grp * 16 + c;
            ushort4 t4 = *(const ushort4*)(em + (size_t)scid[sub][cc] * BB + b);
            float lw = slw[sub][cc];
            float4 t;
            t.x = bf2f(t4.x) + lw; t.y = bf2f(t4.y) + lw;
            t.z = bf2f(t4.z) + lw; t.w = bf2f(t4.w) + lw;
            v[c] = t;
            gmx.x = fmaxf(gmx.x, t.x); gmx.y = fmaxf(gmx.y, t.y);
            gmx.z = fmaxf(gmx.z, t.z); gmx.w = fmaxf(gmx.w, t.w);
        }
        float4 gsu = {0.f, 0.f, 0.f, 0.f};
        #pragma unroll
        for (int c = 0; c < 16; ++c) {
            gsu.x += fexp2(v[c].x - gmx.x);
            gsu.y += fexp2(v[c].y - gmx.y);
            gsu.z += fexp2(v[c].z - gmx.z);
            gsu.w += fexp2(v[c].w - gmx.w);
        }
        if (grp == 0) {
            mx = gmx; su = gsu;
        } else {
            float4 nmx;
            nmx.x = fmaxf(mx.x, gmx.x); nmx.y = fmaxf(mx.y, gmx.y);
            nmx.z = fmaxf(mx.z, gmx.z); nmx.w = fmaxf(mx.w, gmx.w);
            su.x = su.x * fexp2(mx.x - nmx.x) + gsu.x * fexp2(gmx.x - nmx.x);
            su.y = su.y * fexp2(mx.y - nmx.y) + gsu.y * fexp2(gmx.y - nmx.y);
            su.z = su.z * fexp2(mx.z - nmx.z) + gsu.z * fexp2(gmx.z - nmx.z);
            su.w = su.w * fexp2(mx.w - nmx.w) + gsu.w * fexp2(gmx.w - nmx.w);
            mx = nmx;
        }
    }
    float4 o;
    o.x = mx.x + flog2(su.x);
    o.y = mx.y + flog2(su.y);
    o.z = mx.z + flog2(su.z);
    o.w = mx.w + flog2(su.w);
    *(float4*)(out + (size_t)s * BB + b) = o;
}

// ---------------------------------------------------------------------------
// fused root (prod4+sum4): root references only 32 of the 1024 layer-4
// elements, so compute them on the fly from nm (fp32). 8 blocks (1/chunk) x
// 128 threads (1 col each). Output in ln domain.
// ---------------------------------------------------------------------------
__global__ void __launch_bounds__(W) k_root(const float* __restrict__ nm,
                                            const int* __restrict__ pids,
                                            const int* __restrict__ cids,
                                            const float* __restrict__ w,
                                            float* __restrict__ out) {
    int chunk = blockIdx.x;
    int t = threadIdx.x;
    __shared__ float slw[CC];
    __shared__ int sp0[CC], sp1[CC];
    if (t < CC) {
        float lw = w[t];
        float m = lw;
        #pragma unroll
        for (int d = 16; d; d >>= 1) m = fmaxf(m, __shfl_xor(m, d, 32));
        float su = __expf(lw - m);
        #pragma unroll
        for (int d = 16; d; d >>= 1) su += __shfl_xor(su, d, 32);
        slw[t] = (lw - m) * LOG2E - flog2(su);
        int e = cids[t] - 1;
        sp0[t] = pids[e * 2 + 0];
        sp1[t] = pids[e * 2 + 1];
    }
    __syncthreads();
    int b = chunk * W + t;
    float v[CC];
    float mx = -INFINITY;
    #pragma unroll
    for (int c = 0; c < CC; ++c) {
        v[c] = nm[(size_t)sp0[c] * BB + b] + nm[(size_t)sp1[c] * BB + b] + slw[c];
        mx = fmaxf(mx, v[c]);
    }
    float su = 0.f;
    #pragma unroll
    for (int c = 0; c < CC; ++c) su += fexp2(v[c] - mx);
    out[b] = (mx + flog2(su)) * LN2;
}

// ---------------------------------------------------------------------------
// Launch. nm rows = global node ids 0..15360 (row 0 never referenced).
// nm fp32 / em bf16, both log2 domain; root converts back by ln2.
// ---------------------------------------------------------------------------
extern "C" void kernel_launch(void* const* d_in, const int* in_sizes, int n_in,
                              void* d_out, int out_size, void* d_ws, size_t ws_size,
                              hipStream_t stream) {
    const int*   x         = (const int*)  d_in[0];
    const float* in_logits = (const float*)d_in[1];
    const float* w1        = (const float*)d_in[2];
    const float* w2        = (const float*)d_in[3];
    const float* w3        = (const float*)d_in[4];
    const float* w4        = (const float*)d_in[5];
    const int*   pids1     = (const int*)  d_in[6];
    const int*   pids2     = (const int*)  d_in[7];
    const int*   pids3     = (const int*)  d_in[8];
    const int*   pids4     = (const int*)  d_in[9];
    const int*   cids1     = (const int*)  d_in[10];
    const int*   cids2     = (const int*)  d_in[11];
    const int*   cids3     = (const int*)  d_in[12];
    const int*   cids4     = (const int*)  d_in[13];
    float* out = (float*)d_out;

    float*          nm = (float*)d_ws;                      // 15361*1024 f32
    unsigned short* em = (unsigned short*)(nm + (size_t)15361 * BB);  // 8192*1024 bf16
    float*          lp = (float*)(em + (size_t)8192 * BB);  // 8192*64 f32
    int*            xt = (int*)(lp + (size_t)N0 * KK);      // 256*1024 i32

    k_transpose_x <<<(VV * BB) / 256, 256, 0, stream>>>(x, xt);
    k_logsoftmax  <<<N0 / 4, 256, 0, stream>>>(in_logits, lp);
    k_input_gather<<<(N0 / 8) * 8, W, 0, stream>>>(lp, xt, nm);

    // layer pair 1: E=8192 -> S=4096 (global ids 8193..12288)
    k_prod_layer<<<(8192 / 8) * 8, 256, 0, stream>>>(nm, pids1, em);
    k_sum_layer <<<(4096 / 8) * 8, 256, 0, stream>>>(em, cids1, w1, nm + (size_t)8193 * BB, 4096);
    // layer pair 2: E=4096 -> S=2048 (ids 12289..14336)
    k_prod_layer<<<(4096 / 8) * 8, 256, 0, stream>>>(nm, pids2, em);
    k_sum_layer <<<(2048 / 8) * 8, 256, 0, stream>>>(em, cids2, w2, nm + (size_t)12289 * BB, 2048);
    // layer pair 3: E=2048 -> S=1024 (ids 14337..15360)
    k_prod_layer<<<(2048 / 8) * 8, 256, 0, stream>>>(nm, pids3, em);
    k_sum_layer <<<(1024 / 8) * 8, 256, 0, stream>>>(em, cids3, w3, nm + (size_t)14337 * BB, 1024);
    // layer pair 4 fused: root references only 32 elements -> compute on the fly
    k_root<<<8, W, 0, stream>>>(nm, pids4, cids4, w4, out);
}